// Round 8
// baseline (239.129 us; speedup 1.0000x reference)
//
#include <hip/hip_runtime.h>
#include <hip/hip_bf16.h>

#define Dc   192
#define D2c  384
#define NYc  2304   // 48*48

// 1/sqrt(192) * log2(e): folded into wq weights+bias so QK^T scores are in
// log2 domain and softmax uses raw v_exp_f32 (= 2^x).
#define QSCALE 0.1041175462f

typedef __attribute__((ext_vector_type(8))) short short8;
typedef __attribute__((ext_vector_type(4))) float f32x4;

__device__ __forceinline__ unsigned short f2bf(float f) {
    unsigned int u = __float_as_uint(f);
    u += 0x7FFFu + ((u >> 16) & 1u);   // RNE
    return (unsigned short)(u >> 16);
}
__device__ __forceinline__ float bf2f(unsigned short u) {
    return __uint_as_float((unsigned)u << 16);
}
__device__ __forceinline__ float fexp2(float x) {
    float r; asm("v_exp_f32 %0, %1" : "=v"(r) : "v"(x)); return r;
}
__device__ __forceinline__ unsigned cvtpk(float lo, float hi) {
    unsigned r; asm("v_cvt_pk_bf16_f32 %0, %1, %2" : "=v"(r) : "v"(lo), "v"(hi));
    return r;
}
// bijective XCD-chunk swizzle (any nwg)
__device__ __forceinline__ int swzb(int orig, int nwg) {
    int q = nwg >> 3, r = nwg & 7, x = orig & 7;
    int base = (x < r) ? x * (q + 1) : r * (q + 1) + (x - r) * q;
    return base + (orig >> 3);
}

// ---------------------------------------------------------------------------
// pe2d tables: peY[c][p] (384x48), peS[c][p] (192x48)
// ---------------------------------------------------------------------------
__global__ __launch_bounds__(256)
void build_pe_kernel(float* __restrict__ peY, float* __restrict__ peS) {
    int idx = blockIdx.x * 256 + threadIdx.x;    // 27648 total
    int c, p, C; float* dst; int off;
    if (idx < 18432) { c = idx / 48; p = idx % 48; C = 384; dst = peY; off = idx; }
    else { int k = idx - 18432; c = k / 48; p = k % 48; C = 192; dst = peS; off = k; }
    int dh = C >> 1;
    int i = ((c < dh) ? c : c - dh) >> 1;
    float divv = expf((float)(2 * i) * (-9.210340371976184f / (float)dh));
    float ang = (float)p * divv;
    dst[off] = (c & 1) ? cosf(ang) : sinf(ang);
}

// PE add + LDS-tiled transpose to token-major bf16 (y and s; s keeps fp32 ch-major)
__global__ __launch_bounds__(256)
void prep_pe_kernel(const float* __restrict__ y, const float* __restrict__ s,
                    const float* __restrict__ peY, const float* __restrict__ peS,
                    unsigned short* __restrict__ ytok, unsigned short* __restrict__ stok,
                    float* __restrict__ sch) {
    __shared__ unsigned short T[64][66];
    int bid = blockIdx.x;
    int b, ct, nt, C; const float* in; const float* pe; unsigned short* outp; bool isS;
    if (bid < 432) { isS = false; b = bid / 216; int r = bid % 216; ct = r / 36; nt = r % 36;
                     in = y; pe = peY; outp = ytok; C = 384; }
    else { int l = bid - 432; isS = true; b = l / 108; int r = l % 108; ct = r / 36; nt = r % 36;
           in = s; pe = peS; outp = stok; C = 192; }
    int t = threadIdx.x;
    int nl = t & 63;
    int n = nt * 64 + nl;
    int pos_x = n % 48, pos_y = n / 48;
    #pragma unroll
    for (int i = 0; i < 16; ++i) {
        int cl = (t >> 6) + 4 * i;
        int c = ct * 64 + cl;
        int pos = (c < (C >> 1)) ? pos_x : pos_y;
        long gi = (long)b * C * NYc + (long)c * NYc + n;
        float v = in[gi] + pe[c * 48 + pos];
        if (isS) sch[gi] = v;
        T[nl][cl] = f2bf(v);
    }
    __syncthreads();
    #pragma unroll
    for (int i = 0; i < 8; ++i) {
        int nl2 = (t >> 5) + 8 * i;
        int cp  = t & 31;
        unsigned u = (unsigned)T[nl2][2 * cp] | ((unsigned)T[nl2][2 * cp + 1] << 16);
        long row = (long)b * NYc + nt * 64 + nl2;
        *(unsigned*)(outp + row * C + ct * 64 + 2 * cp) = u;
    }
}

// weights: seven 1x1 mats bf16 (wq pre-scaled) + qk bias + up_w transpose to
// upT [j=tap*384+c][m] + c3b[o] = conv3_w[o,:]@up_b + conv3_b[o]
__global__ __launch_bounds__(256)
void prep_w_kernel(const float* __restrict__ w0, const float* __restrict__ w1,
                   const float* __restrict__ w2, const float* __restrict__ w3,
                   const float* __restrict__ w4, const float* __restrict__ w5,
                   const float* __restrict__ w6, unsigned short* __restrict__ dst,
                   const float* __restrict__ wq_b, const float* __restrict__ wk_b,
                   float* __restrict__ qkb,
                   const float* __restrict__ upw, unsigned short* __restrict__ upT,
                   const float* __restrict__ up_b, const float* __restrict__ conv3_b,
                   float* __restrict__ c3b) {
    int idx = blockIdx.x * 256 + threadIdx.x;    // 1953792 + 192
    if (idx < 626688) {
        if (idx < 768)
            qkb[idx] = (idx < 384) ? wq_b[idx] * QSCALE : wk_b[idx - 384];
        const float* src; int off; float scl = 1.0f;
        if      (idx < 147456) { src = w0; off = idx; }
        else if (idx < 294912) { src = w1; off = idx - 147456; scl = QSCALE; }
        else if (idx < 442368) { src = w2; off = idx - 294912; }
        else if (idx < 479232) { src = w3; off = idx - 442368; }
        else if (idx < 516096) { src = w4; off = idx - 479232; }
        else if (idx < 552960) { src = w5; off = idx - 516096; }
        else                   { src = w6; off = idx - 552960; }
        dst[idx] = f2bf(src[off] * scl);
    } else if (idx < 1953792) {
        int k = idx - 626688;                    // upT[j][m] = up_w[m][c][tap]
        int j = k / 384, m = k % 384;
        int tap = j / 384, c = j % 384;
        upT[k] = f2bf(upw[((long)m * 384 + c) * 9 + tap]);
    } else if (idx < 1953984) {
        int o = idx - 1953792;                   // c3b fold (w6 = conv3_w)
        float acc = 0.f;
        for (int m = 0; m < 384; ++m) acc += w6[o * 384 + m] * up_b[m];
        c3b[o] = acc + conv3_b[o];
    }
}

// ---------------------------------------------------------------------------
// Fused multi-segment bf16 MFMA GEMM. 64x64 tile, 4 waves (32x32), BK=64,
// double-buffered LDS (one barrier per K-step).
// flags: 1=B-side im2col, 2=BN+ReLU, 4=f32 out, 8=ch-major out, 16=sig-gate,
//        32=no bias.
// ---------------------------------------------------------------------------
struct Seg {
    const unsigned short* A; const unsigned short* B;
    int aP, bP, K, nT, blkOff, nBlk, flags, nSplit;
    long oSplitBytes;
    const float *bias, *bng, *bnb;
    char* out; int oPitch; long oBatch;
};

template<int NSEG>
__global__ __launch_bounds__(256)
void fused_gemm(Seg s0, Seg s1, Seg s2, const float* __restrict__ smul)
{
    int raw = blockIdx.x;
    Seg sg = s0;
    if (NSEG > 1 && raw >= s1.blkOff) sg = s1;
    if (NSEG > 2 && raw >= s2.blkOff) sg = s2;
    int local = swzb(raw - sg.blkOff, sg.nBlk);
    int kBase = 0;
    if (sg.nSplit > 1) {
        int pc = sg.nBlk / sg.nSplit;
        int g = local / pc; local -= g * pc;
        sg.A += (long)g * sg.K;
        sg.out += (long)g * sg.oSplitBytes;
        kBase = g * sg.K;
    }
    int mt = local / sg.nT, nt = local - mt * sg.nT;
    int m0 = mt * 64, n0 = nt * 64;

    __shared__ __align__(16) unsigned short As[2][64][72];
    __shared__ __align__(16) unsigned short Bs[2][64][72];

    int t = threadIdx.x, lane = t & 63, w = t >> 6;
    int lr = lane & 15, lg = lane >> 4;
    int wm = (w >> 1) * 32, wn = (w & 1) * 32;

    f32x4 acc[2][2];
    #pragma unroll
    for (int i = 0; i < 2; ++i)
        #pragma unroll
        for (int j = 0; j < 2; ++j)
            acc[i][j] = (f32x4){0.f, 0.f, 0.f, 0.f};

    uint4 ra[2], rb[2];
    bool im2colB = (sg.flags & 1) != 0;

    auto load = [&](int k0) {
        #pragma unroll
        for (int i = 0; i < 2; ++i) {
            int idx = t + i * 256, row = idx >> 3, sl = idx & 7;
            ra[i] = *(const uint4*)(sg.A + (long)(m0 + row) * sg.aP + k0 + sl * 8);
            if (im2colB) {
                int tok = n0 + row;
                int bb = tok >= NYc;
                int n = tok - bb * NYc;
                int kk = kBase + k0;
                int tap = kk / 384;
                int rem = kk - tap * 384 + sl * 8;
                int py = n / 48 + tap / 3 - 1;
                int px = n % 48 + tap % 3 - 1;
                rb[i] = (py >= 0 && py < 48 && px >= 0 && px < 48)
                    ? *(const uint4*)(sg.B + ((long)bb * NYc + py * 48 + px) * sg.bP + rem)
                    : make_uint4(0, 0, 0, 0);
            } else {
                rb[i] = *(const uint4*)(sg.B + (long)(n0 + row) * sg.bP + k0 + sl * 8);
            }
        }
    };
    auto store = [&](int buf) {
        #pragma unroll
        for (int i = 0; i < 2; ++i) {
            int idx = t + i * 256;
            *(uint4*)&As[buf][idx >> 3][(idx & 7) * 8] = ra[i];
            *(uint4*)&Bs[buf][idx >> 3][(idx & 7) * 8] = rb[i];
        }
    };

    load(0); store(0); __syncthreads();
    int NT = sg.K >> 6;
    int cur = 0;
    for (int tt = 0; tt < NT; ++tt) {
        bool more = (tt + 1 < NT);
        if (more) load((tt + 1) << 6);           // issue-early prefetch
        #pragma unroll
        for (int kk = 0; kk < 2; ++kk) {
            short8 a0 = *(const short8*)&As[cur][wm + lr][kk * 32 + lg * 8];
            short8 a1 = *(const short8*)&As[cur][wm + 16 + lr][kk * 32 + lg * 8];
            short8 b0 = *(const short8*)&Bs[cur][wn + lr][kk * 32 + lg * 8];
            short8 b1 = *(const short8*)&Bs[cur][wn + 16 + lr][kk * 32 + lg * 8];
            acc[0][0] = __builtin_amdgcn_mfma_f32_16x16x32_bf16(a0, b0, acc[0][0], 0, 0, 0);
            acc[0][1] = __builtin_amdgcn_mfma_f32_16x16x32_bf16(a0, b1, acc[0][1], 0, 0, 0);
            acc[1][0] = __builtin_amdgcn_mfma_f32_16x16x32_bf16(a1, b0, acc[1][0], 0, 0, 0);
            acc[1][1] = __builtin_amdgcn_mfma_f32_16x16x32_bf16(a1, b1, acc[1][1], 0, 0, 0);
        }
        if (more) store(cur ^ 1);                // other buffer: no pre-barrier
        __syncthreads();
        cur ^= 1;
    }

    #pragma unroll
    for (int i = 0; i < 2; ++i)
    #pragma unroll
    for (int j = 0; j < 2; ++j)
    #pragma unroll
    for (int r = 0; r < 4; ++r) {
        int gm = m0 + wm + i * 16 + lg * 4 + r;
        int gn = n0 + wn + j * 16 + lr;
        int ch = (sg.flags & 8) ? gm : gn;
        float v = acc[i][j][r];
        if (!(sg.flags & 32)) v += sg.bias[ch];
        if (sg.flags & 2)
            v = fmaxf(fmaf(v, sg.bng[ch], sg.bnb[ch]), 0.f);
        long o; int b = 0, tok = gn;
        if (sg.flags & 8) {
            b = gn >= NYc; tok = gn - b * NYc;
            o = (long)b * sg.oBatch + (long)gm * sg.oPitch + tok;
        } else {
            o = (long)gm * sg.oPitch + gn;
        }
        if (sg.flags & 16) {
            v = fmaf(v, sg.bng[ch], sg.bnb[ch]);
            v = 1.f / (1.f + __expf(-v));
            v *= smul[(long)b * 442368 + (long)gm * NYc + tok];
        }
        if (sg.flags & 4) ((float*)sg.out)[o] = v;
        else              ((unsigned short*)sg.out)[o] = f2bf(v);
    }
}

// ---------------------------------------------------------------------------
// reduce 3 bf16 split-K partials + fused bias + BN3 + ReLU -> d_out[192:384) f32
// ---------------------------------------------------------------------------
__global__ __launch_bounds__(256)
void reduce_up_kernel(const unsigned short* __restrict__ part,
                      const float* __restrict__ c3b,
                      const float* __restrict__ bn3g, const float* __restrict__ bn3b,
                      float* __restrict__ out) {
    int tid = blockIdx.x * 256 + threadIdx.x;   // 221184
    int e = tid * 4;
    int b = e / 442368; int r = e - b * 442368;
    int o = r / 2304;
    ushort4 p0 = *(const ushort4*)(part + e);
    ushort4 p1 = *(const ushort4*)(part + 884736 + e);
    ushort4 p2 = *(const ushort4*)(part + 1769472 + e);
    float g = bn3g[o], bb = bn3b[o], cb = c3b[o];
    float4 res;
    float* rp = (float*)&res;
    unsigned short* q0 = (unsigned short*)&p0;
    unsigned short* q1 = (unsigned short*)&p1;
    unsigned short* q2 = (unsigned short*)&p2;
    #pragma unroll
    for (int j = 0; j < 4; ++j) {
        float v = bf2f(q0[j]) + bf2f(q1[j]) + bf2f(q2[j]) + cb;
        rp[j] = fmaxf(fmaf(v, g, bb), 0.f);
    }
    *(float4*)(out + (long)b * 884736 + 442368 + r) = res;
}

// ---------------------------------------------------------------------------
// Fused MFMA flash attention, barrier-free main loop.
// All MFMA operands loaded DIRECT FROM GLOBAL (K = rows of QKtok, V = rows of
// Vch are both k-contiguous; teams share fragments -> L1 hits). LDS only for
// the wave-private P round-trip (b64 writes) and the final 2-way combine.
// Grid 1152 = 72 qblocks (32 q) x 16 bh; 256 thr = 4 waves = 2 teams x 2 splits.
// ---------------------------------------------------------------------------
__global__ __launch_bounds__(256)
void attn_kernel(const unsigned short* __restrict__ QK,
                 const unsigned short* __restrict__ Vc,
                 unsigned short* __restrict__ Zt)
{
    int nid = swzb(blockIdx.x, 1152);
    int qb = nid % 72;                   // 0..71 (32 queries each)
    int bh = nid / 72;                   // 0..15
    int b = bh >> 3, h = bh & 7;
    const unsigned short* Qg = QK + (long)b * NYc * 768 + h * 48;
    const unsigned short* Kg = Qg + 384;
    const unsigned short* Vg = Vc + ((long)b * Dc + h * 24) * NYc;
    unsigned short*       Z  = Zt + (long)b * NYc * Dc + h * 24;

    // wave-private P tiles (b64-packed); aliased as combine scratch after loop
    __shared__ __align__(16) uint2 Ps8[4][16][18];

    int t = threadIdx.x, lane = t & 63, w = t >> 6;
    int lr = lane & 15, lg = lane >> 4;
    int tm = w >> 1, hf = w & 1;
    int q0 = qb * 32;

    short8 z8 = {0, 0, 0, 0, 0, 0, 0, 0};
    const unsigned short* qrow = Qg + (long)(q0 + tm * 16 + lr) * 768;
    short8 bq0 = *(const short8*)(qrow + lg * 8);
    short8 bq1 = (lg < 2) ? *(const short8*)(qrow + 32 + lg * 8) : z8;

    float m_run = -1e30f, l_run = 0.f;
    f32x4 O0 = {0.f, 0.f, 0.f, 0.f}, O1 = {0.f, 0.f, 0.f, 0.f};

    for (int kt = 0; kt < 18; ++kt) {
        long k0 = (long)kt * 128 + hf * 64;

        // QK^T: K fragments direct from global (rows of QKtok)
        f32x4 sS[4];
        #pragma unroll
        for (int ks = 0; ks < 4; ++ks) {
            const unsigned short* krow = Kg + (k0 + ks * 16 + lr) * 768 + lg * 8;
            short8 ak0 = *(const short8*)krow;
            short8 ak1 = (lg < 2) ? *(const short8*)(krow + 32) : z8;
            f32x4 c = {0.f, 0.f, 0.f, 0.f};
            c = __builtin_amdgcn_mfma_f32_16x16x32_bf16(ak0, bq0, c, 0, 0, 0);
            c = __builtin_amdgcn_mfma_f32_16x16x32_bf16(ak1, bq1, c, 0, 0, 0);
            sS[ks] = c;
        }

        // V fragments direct from global (rows of Vch), issued early
        const unsigned short* vrow0 = Vg + (long)lr * NYc + k0 + lg * 8;
        short8 bv00 = *(const short8*)vrow0;
        short8 bv01 = *(const short8*)(vrow0 + 32);
        short8 bv10 = z8, bv11 = z8;
        if (lr < 8) {
            const unsigned short* vrow1 = vrow0 + (long)16 * NYc;
            bv10 = *(const short8*)vrow1;
            bv11 = *(const short8*)(vrow1 + 32);
        }

        // online softmax per q row (lane's 16 scores are for q = lr)
        float tmax = -1e30f;
        #pragma unroll
        for (int ks = 0; ks < 4; ++ks)
            #pragma unroll
            for (int r = 0; r < 4; ++r) tmax = fmaxf(tmax, sS[ks][r]);
        tmax = fmaxf(tmax, __shfl_xor(tmax, 16));
        tmax = fmaxf(tmax, __shfl_xor(tmax, 32));

        if (__any(tmax > m_run + 10.f)) {       // deferred rescale (rare)
            float mn = fmaxf(m_run, tmax);
            float al = fexp2(m_run - mn);
            m_run = mn;
            l_run *= al;
            #pragma unroll
            for (int rr = 0; rr < 4; ++rr) {
                float arr = __shfl(al, (lane & 48) | (lg * 4 + rr));
                O0[rr] *= arr; O1[rr] *= arr;
            }
        }

        float psum = 0.f;
        #pragma unroll
        for (int ks = 0; ks < 4; ++ks) {
            float p0 = fexp2(sS[ks][0] - m_run);
            float p1 = fexp2(sS[ks][1] - m_run);
            float p2 = fexp2(sS[ks][2] - m_run);
            float p3 = fexp2(sS[ks][3] - m_run);
            psum += (p0 + p1) + (p2 + p3);
            uint2 u = { cvtpk(p0, p1), cvtpk(p2, p3) };
            Ps8[w][lr][4 * ks + lg] = u;        // b64 write, wave-private
        }
        psum += __shfl_xor(psum, 16);
        psum += __shfl_xor(psum, 32);
        l_run += psum;

        // O += P V
        short8 ap0 = *(const short8*)&Ps8[w][lr][2 * lg];
        short8 ap1 = *(const short8*)&Ps8[w][lr][8 + 2 * lg];
        O0 = __builtin_amdgcn_mfma_f32_16x16x32_bf16(ap0, bv00, O0, 0, 0, 0);
        O0 = __builtin_amdgcn_mfma_f32_16x16x32_bf16(ap1, bv01, O0, 0, 0, 0);
        O1 = __builtin_amdgcn_mfma_f32_16x16x32_bf16(ap0, bv10, O1, 0, 0, 0);
        O1 = __builtin_amdgcn_mfma_f32_16x16x32_bf16(ap1, bv11, O1, 0, 0, 0);
    }

    __syncthreads();    // combine scratch aliases Ps8 — drain all P readers first

    float* Cf = (float*)&Ps8[0][0][0];
    float* T = Cf + tm * 576;
    if (hf == 1) {
        #pragma unroll
        for (int j = 0; j < 4; ++j) {
            T[lane * 8 + j]     = O0[j];
            T[lane * 8 + 4 + j] = O1[j];
        }
        if (lane < 16) { T[512 + lane] = m_run; T[528 + lane] = l_run; }
    }
    __syncthreads();
    if (hf == 0) {
        float mB = T[512 + lr], lB = T[528 + lr];
        float mS = fmaxf(m_run, mB);
        float aA = fexp2(m_run - mS), aB = fexp2(mB - mS);
        float invl = 1.f / (l_run * aA + lB * aB);
        float fA = aA * invl, fB = aB * invl;
        #pragma unroll
        for (int rr = 0; rr < 4; ++rr) {
            int src = (lane & 48) | (lg * 4 + rr);
            float gA = __shfl(fA, src), gB = __shfl(fB, src);
            int n = q0 + tm * 16 + lg * 4 + rr;
            unsigned short* zr = Z + (long)n * Dc;
            float z0 = O0[rr] * gA + T[lane * 8 + rr] * gB;
            zr[lr] = f2bf(z0);
            if (lr < 8) {
                float z1 = O1[rr] * gA + T[lane * 8 + 4 + rr] * gB;
                zr[16 + lr] = f2bf(z1);
            }
        }
    }
}

// ---------------------------------------------------------------------------
extern "C" void kernel_launch(void* const* d_in, const int* in_sizes, int n_in,
                              void* d_out, int out_size, void* d_ws, size_t ws_size,
                              hipStream_t stream) {
    const float* y       = (const float*)d_in[0];
    const float* s       = (const float*)d_in[1];
    const float* wq_w    = (const float*)d_in[2];
    const float* wq_b    = (const float*)d_in[3];
    const float* wk_w    = (const float*)d_in[4];
    const float* wk_b    = (const float*)d_in[5];
    const float* wv_w    = (const float*)d_in[6];
    const float* wv_b    = (const float*)d_in[7];
    const float* conv1_w = (const float*)d_in[8];
    const float* conv1_b = (const float*)d_in[9];
    const float* bn1_g   = (const float*)d_in[10];
    const float* bn1_b   = (const float*)d_in[11];
    const float* conv2_w = (const float*)d_in[12];
    const float* conv2_b = (const float*)d_in[13];
    const float* bn2_g   = (const float*)d_in[14];
    const float* bn2_b   = (const float*)d_in[15];
    const float* up_w    = (const float*)d_in[16];
    const float* up_b    = (const float*)d_in[17];
    const float* conv3_w = (const float*)d_in[18];
    const float* conv3_b = (const float*)d_in[19];
    const float* bn3_g   = (const float*)d_in[20];
    const float* bn3_b   = (const float*)d_in[21];
    const float* sig_w   = (const float*)d_in[22];
    const float* sig_b   = (const float*)d_in[23];
    const float* bnsig_g = (const float*)d_in[24];
    const float* bnsig_b = (const float*)d_in[25];

    unsigned short* wsp   = (unsigned short*)d_ws;
    unsigned short* wcvt  = wsp;                     // 626688
    unsigned short* upT   = wcvt + 626688;           // 1327104 [3456][384]
    unsigned short* Wc    = upT + 1327104;           //  663552 [192][3456]
    unsigned short* y_pe  = Wc + 663552;             // 1769472 [4608][384]
    unsigned short* s_pe  = y_pe + 1769472;          //  884736 [4608][192]
    unsigned short* y_c1  = s_pe + 884736;           // 1769472
    unsigned short* s_c2  = y_c1 + 1769472;          //  884736
    unsigned short* QKtok = s_c2 + 884736;           // 3538944 [4608][768]
    unsigned short* Vch   = QKtok + 3538944;         //  884736 [b][192][2304]
    unsigned short* partZ = Vch + 884736;            // 2654208 (partials; Ztok aliases)
    unsigned short* Ztok  = partZ;                   //  884736 (lifetime disjoint)
    float*          s_ch  = (float*)(partZ + 2654208); // 884736 fp32
    float*          qkb   = s_ch + 884736;           //  768 fp32
    float*          c3b   = qkb + 768;               //  192 fp32
    float*          peY   = c3b + 192;               //  18432 fp32
    float*          peS   = peY + 18432;             //  9216 fp32

    const unsigned short* conv1wb = wcvt;
    const unsigned short* wqkb    = wcvt + 147456;   // wq||wk, 768 x 384
    const unsigned short* conv2wb = wcvt + 442368;
    const unsigned short* wvb     = wcvt + 479232;
    const unsigned short* sigwb   = wcvt + 516096;
    const unsigned short* conv3wb = wcvt + 552960;

    build_pe_kernel<<<108, 256, 0, stream>>>(peY, peS);
    prep_w_kernel<<<7633, 256, 0, stream>>>(conv1_w, wq_w, wk_w, conv2_w,
                                            wv_w, sig_w, conv3_w, wcvt,
                                            wq_b, wk_b, qkb, up_w, upT,
                                            up_b, conv3_b, c3b);
    prep_pe_kernel<<<648, 256, 0, stream>>>(y, s, peY, peS, y_pe, s_pe, s_ch);

    Seg sz = {};

    // W' = conv3_w @ up_w : A=conv3wb [192][384], B=upT [3456][384] -> Wc [192][3456]
    {
        Seg a = { conv3wb, upT, 384, 384, 384, 54, 0, 162, 32, 1, 0,
                  nullptr, nullptr, nullptr, (char*)Wc, 3456, 0 };
        fused_gemm<1><<<162, 256, 0, stream>>>(a, sz, sz, nullptr);
    }
    // G1: combined up*conv3 split-K=3 (648) + conv1 (432) + conv2 (216) -> 1296
    {
        Seg a = { Wc, y_pe, 3456, 384, 1152, 72, 0, 648, 1 | 8 | 32, 3,
                  (long)884736 * 2,
                  nullptr, nullptr, nullptr, (char*)partZ, NYc, 442368 };
        Seg b = { y_pe, conv1wb, 384, 384, 384, 6, 648, 432, 2, 1, 0,
                  conv1_b, bn1_g, bn1_b, (char*)y_c1, 384, 0 };
        Seg c = { s_pe, conv2wb, 192, 192, 192, 3, 1080, 216, 2, 1, 0,
                  conv2_b, bn2_g, bn2_b, (char*)s_c2, 192, 0 };
        fused_gemm<3><<<1296, 256, 0, stream>>>(a, b, c, nullptr);
    }
    // G2: QK (864) + V (216) -> 1080
    {
        Seg a = { y_c1, wqkb, 384, 384, 384, 12, 0, 864, 0, 1, 0,
                  qkb, nullptr, nullptr, (char*)QKtok, 768, 0 };
        Seg b = { wvb, s_c2, 192, 192, 192, 72, 864, 216, 8, 1, 0,
                  wv_b, nullptr, nullptr, (char*)Vch, NYc, 442368 };
        fused_gemm<2><<<1080, 256, 0, stream>>>(a, b, sz, nullptr);
    }
    // reduce split-K partials -> d_out[192:384) fp32 (with bn3+relu)
    reduce_up_kernel<<<864, 256, 0, stream>>>(partZ, c3b, bn3_g, bn3_b,
                                              (float*)d_out);
    // attention (barrier-free, direct-global fragments)
    attn_kernel<<<1152, 256, 0, stream>>>(QKtok, Vch, Ztok);
    // G4: sigmoid gate (216)
    {
        Seg a = { sigwb, Ztok, 192, 192, 192, 72, 0, 216, 4 | 8 | 16, 1, 0,
                  sig_b, bnsig_g, bnsig_b, (char*)d_out, NYc, 884736 };
        fused_gemm<1><<<216, 256, 0, stream>>>(a, sz, sz, s_ch);
    }
}

// Round 9
// 224.374 us; speedup vs baseline: 1.0658x; 1.0658x over previous
//
#include <hip/hip_runtime.h>
#include <hip/hip_bf16.h>

#define Dc   192
#define D2c  384
#define NYc  2304   // 48*48

// 1/sqrt(192) * log2(e): folded into wq weights+bias so QK^T scores are in
// log2 domain and softmax uses raw v_exp_f32 (= 2^x).
#define QSCALE 0.1041175462f

typedef __attribute__((ext_vector_type(8))) short short8;
typedef __attribute__((ext_vector_type(4))) float f32x4;

__device__ __forceinline__ unsigned short f2bf(float f) {
    unsigned int u = __float_as_uint(f);
    u += 0x7FFFu + ((u >> 16) & 1u);   // RNE
    return (unsigned short)(u >> 16);
}
__device__ __forceinline__ float bf2f(unsigned short u) {
    return __uint_as_float((unsigned)u << 16);
}
__device__ __forceinline__ float fexp2(float x) {
    float r; asm("v_exp_f32 %0, %1" : "=v"(r) : "v"(x)); return r;
}
__device__ __forceinline__ unsigned cvtpk(float lo, float hi) {
    unsigned r; asm("v_cvt_pk_bf16_f32 %0, %1, %2" : "=v"(r) : "v"(lo), "v"(hi));
    return r;
}
// bijective XCD-chunk swizzle (any nwg)
__device__ __forceinline__ int swzb(int orig, int nwg) {
    int q = nwg >> 3, r = nwg & 7, x = orig & 7;
    int base = (x < r) ? x * (q + 1) : r * (q + 1) + (x - r) * q;
    return base + (orig >> 3);
}

// ---------------------------------------------------------------------------
// pe2d tables: peY[c][p] (384x48), peS[c][p] (192x48)
// ---------------------------------------------------------------------------
__global__ __launch_bounds__(256)
void build_pe_kernel(float* __restrict__ peY, float* __restrict__ peS) {
    int idx = blockIdx.x * 256 + threadIdx.x;    // 27648 total
    int c, p, C; float* dst; int off;
    if (idx < 18432) { c = idx / 48; p = idx % 48; C = 384; dst = peY; off = idx; }
    else { int k = idx - 18432; c = k / 48; p = k % 48; C = 192; dst = peS; off = k; }
    int dh = C >> 1;
    int i = ((c < dh) ? c : c - dh) >> 1;
    float divv = expf((float)(2 * i) * (-9.210340371976184f / (float)dh));
    float ang = (float)p * divv;
    dst[off] = (c & 1) ? cosf(ang) : sinf(ang);
}

// PE add + LDS-tiled transpose to token-major bf16 (y and s; s keeps fp32 ch-major)
__global__ __launch_bounds__(256)
void prep_pe_kernel(const float* __restrict__ y, const float* __restrict__ s,
                    const float* __restrict__ peY, const float* __restrict__ peS,
                    unsigned short* __restrict__ ytok, unsigned short* __restrict__ stok,
                    float* __restrict__ sch) {
    __shared__ unsigned short T[64][66];
    int bid = blockIdx.x;
    int b, ct, nt, C; const float* in; const float* pe; unsigned short* outp; bool isS;
    if (bid < 432) { isS = false; b = bid / 216; int r = bid % 216; ct = r / 36; nt = r % 36;
                     in = y; pe = peY; outp = ytok; C = 384; }
    else { int l = bid - 432; isS = true; b = l / 108; int r = l % 108; ct = r / 36; nt = r % 36;
           in = s; pe = peS; outp = stok; C = 192; }
    int t = threadIdx.x;
    int nl = t & 63;
    int n = nt * 64 + nl;
    int pos_x = n % 48, pos_y = n / 48;
    #pragma unroll
    for (int i = 0; i < 16; ++i) {
        int cl = (t >> 6) + 4 * i;
        int c = ct * 64 + cl;
        int pos = (c < (C >> 1)) ? pos_x : pos_y;
        long gi = (long)b * C * NYc + (long)c * NYc + n;
        float v = in[gi] + pe[c * 48 + pos];
        if (isS) sch[gi] = v;
        T[nl][cl] = f2bf(v);
    }
    __syncthreads();
    #pragma unroll
    for (int i = 0; i < 8; ++i) {
        int nl2 = (t >> 5) + 8 * i;
        int cp  = t & 31;
        unsigned u = (unsigned)T[nl2][2 * cp] | ((unsigned)T[nl2][2 * cp + 1] << 16);
        long row = (long)b * NYc + nt * 64 + nl2;
        *(unsigned*)(outp + row * C + ct * 64 + 2 * cp) = u;
    }
}

// weights: seven 1x1 mats bf16 (wq pre-scaled) + qk bias + up_w transpose to
// upT [j=tap*384+c][m] + c3b[o] = conv3_w[o,:]@up_b + conv3_b[o]
__global__ __launch_bounds__(256)
void prep_w_kernel(const float* __restrict__ w0, const float* __restrict__ w1,
                   const float* __restrict__ w2, const float* __restrict__ w3,
                   const float* __restrict__ w4, const float* __restrict__ w5,
                   const float* __restrict__ w6, unsigned short* __restrict__ dst,
                   const float* __restrict__ wq_b, const float* __restrict__ wk_b,
                   float* __restrict__ qkb,
                   const float* __restrict__ upw, unsigned short* __restrict__ upT,
                   const float* __restrict__ up_b, const float* __restrict__ conv3_b,
                   float* __restrict__ c3b) {
    int idx = blockIdx.x * 256 + threadIdx.x;    // 1953792 + 192
    if (idx < 626688) {
        if (idx < 768)
            qkb[idx] = (idx < 384) ? wq_b[idx] * QSCALE : wk_b[idx - 384];
        const float* src; int off; float scl = 1.0f;
        if      (idx < 147456) { src = w0; off = idx; }
        else if (idx < 294912) { src = w1; off = idx - 147456; scl = QSCALE; }
        else if (idx < 442368) { src = w2; off = idx - 294912; }
        else if (idx < 479232) { src = w3; off = idx - 442368; }
        else if (idx < 516096) { src = w4; off = idx - 479232; }
        else if (idx < 552960) { src = w5; off = idx - 516096; }
        else                   { src = w6; off = idx - 552960; }
        dst[idx] = f2bf(src[off] * scl);
    } else if (idx < 1953792) {
        int k = idx - 626688;                    // upT[j][m] = up_w[m][c][tap]
        int j = k / 384, m = k % 384;
        int tap = j / 384, c = j % 384;
        upT[k] = f2bf(upw[((long)m * 384 + c) * 9 + tap]);
    } else if (idx < 1953984) {
        int o = idx - 1953792;                   // c3b fold (w6 = conv3_w)
        float acc = 0.f;
        for (int m = 0; m < 384; ++m) acc += w6[o * 384 + m] * up_b[m];
        c3b[o] = acc + conv3_b[o];
    }
}

// ---------------------------------------------------------------------------
// Fused multi-segment bf16 MFMA GEMM. 64x64 tile, 4 waves (32x32), BK=64,
// double-buffered LDS (one barrier per K-step).
// flags: 1=B-side im2col, 2=BN+ReLU, 4=f32 out, 8=ch-major out, 16=sig-gate,
//        32=no bias.
// ---------------------------------------------------------------------------
struct Seg {
    const unsigned short* A; const unsigned short* B;
    int aP, bP, K, nT, blkOff, nBlk, flags, nSplit;
    long oSplitBytes;
    const float *bias, *bng, *bnb;
    char* out; int oPitch; long oBatch;
};

template<int NSEG>
__global__ __launch_bounds__(256)
void fused_gemm(Seg s0, Seg s1, Seg s2, const float* __restrict__ smul)
{
    int raw = blockIdx.x;
    Seg sg = s0;
    if (NSEG > 1 && raw >= s1.blkOff) sg = s1;
    if (NSEG > 2 && raw >= s2.blkOff) sg = s2;
    int local = swzb(raw - sg.blkOff, sg.nBlk);
    int kBase = 0;
    if (sg.nSplit > 1) {
        int pc = sg.nBlk / sg.nSplit;
        int g = local / pc; local -= g * pc;
        sg.A += (long)g * sg.K;
        sg.out += (long)g * sg.oSplitBytes;
        kBase = g * sg.K;
    }
    int mt = local / sg.nT, nt = local - mt * sg.nT;
    int m0 = mt * 64, n0 = nt * 64;

    __shared__ __align__(16) unsigned short As[2][64][72];
    __shared__ __align__(16) unsigned short Bs[2][64][72];

    int t = threadIdx.x, lane = t & 63, w = t >> 6;
    int lr = lane & 15, lg = lane >> 4;
    int wm = (w >> 1) * 32, wn = (w & 1) * 32;

    f32x4 acc[2][2];
    #pragma unroll
    for (int i = 0; i < 2; ++i)
        #pragma unroll
        for (int j = 0; j < 2; ++j)
            acc[i][j] = (f32x4){0.f, 0.f, 0.f, 0.f};

    uint4 ra[2], rb[2];
    bool im2colB = (sg.flags & 1) != 0;

    auto load = [&](int k0) {
        #pragma unroll
        for (int i = 0; i < 2; ++i) {
            int idx = t + i * 256, row = idx >> 3, sl = idx & 7;
            ra[i] = *(const uint4*)(sg.A + (long)(m0 + row) * sg.aP + k0 + sl * 8);
            if (im2colB) {
                int tok = n0 + row;
                int bb = tok >= NYc;
                int n = tok - bb * NYc;
                int kk = kBase + k0;
                int tap = kk / 384;
                int rem = kk - tap * 384 + sl * 8;
                int py = n / 48 + tap / 3 - 1;
                int px = n % 48 + tap % 3 - 1;
                rb[i] = (py >= 0 && py < 48 && px >= 0 && px < 48)
                    ? *(const uint4*)(sg.B + ((long)bb * NYc + py * 48 + px) * sg.bP + rem)
                    : make_uint4(0, 0, 0, 0);
            } else {
                rb[i] = *(const uint4*)(sg.B + (long)(n0 + row) * sg.bP + k0 + sl * 8);
            }
        }
    };
    auto store = [&](int buf) {
        #pragma unroll
        for (int i = 0; i < 2; ++i) {
            int idx = t + i * 256;
            *(uint4*)&As[buf][idx >> 3][(idx & 7) * 8] = ra[i];
            *(uint4*)&Bs[buf][idx >> 3][(idx & 7) * 8] = rb[i];
        }
    };

    load(0); store(0); __syncthreads();
    int NT = sg.K >> 6;
    int cur = 0;
    for (int tt = 0; tt < NT; ++tt) {
        bool more = (tt + 1 < NT);
        if (more) load((tt + 1) << 6);           // issue-early prefetch
        #pragma unroll
        for (int kk = 0; kk < 2; ++kk) {
            short8 a0 = *(const short8*)&As[cur][wm + lr][kk * 32 + lg * 8];
            short8 a1 = *(const short8*)&As[cur][wm + 16 + lr][kk * 32 + lg * 8];
            short8 b0 = *(const short8*)&Bs[cur][wn + lr][kk * 32 + lg * 8];
            short8 b1 = *(const short8*)&Bs[cur][wn + 16 + lr][kk * 32 + lg * 8];
            acc[0][0] = __builtin_amdgcn_mfma_f32_16x16x32_bf16(a0, b0, acc[0][0], 0, 0, 0);
            acc[0][1] = __builtin_amdgcn_mfma_f32_16x16x32_bf16(a0, b1, acc[0][1], 0, 0, 0);
            acc[1][0] = __builtin_amdgcn_mfma_f32_16x16x32_bf16(a1, b0, acc[1][0], 0, 0, 0);
            acc[1][1] = __builtin_amdgcn_mfma_f32_16x16x32_bf16(a1, b1, acc[1][1], 0, 0, 0);
        }
        if (more) store(cur ^ 1);                // other buffer: no pre-barrier
        __syncthreads();
        cur ^= 1;
    }

    #pragma unroll
    for (int i = 0; i < 2; ++i)
    #pragma unroll
    for (int j = 0; j < 2; ++j)
    #pragma unroll
    for (int r = 0; r < 4; ++r) {
        int gm = m0 + wm + i * 16 + lg * 4 + r;
        int gn = n0 + wn + j * 16 + lr;
        int ch = (sg.flags & 8) ? gm : gn;
        float v = acc[i][j][r];
        if (!(sg.flags & 32)) v += sg.bias[ch];
        if (sg.flags & 2)
            v = fmaxf(fmaf(v, sg.bng[ch], sg.bnb[ch]), 0.f);
        long o; int b = 0, tok = gn;
        if (sg.flags & 8) {
            b = gn >= NYc; tok = gn - b * NYc;
            o = (long)b * sg.oBatch + (long)gm * sg.oPitch + tok;
        } else {
            o = (long)gm * sg.oPitch + gn;
        }
        if (sg.flags & 16) {
            v = fmaf(v, sg.bng[ch], sg.bnb[ch]);
            v = 1.f / (1.f + __expf(-v));
            v *= smul[(long)b * 442368 + (long)gm * NYc + tok];
        }
        if (sg.flags & 4) ((float*)sg.out)[o] = v;
        else              ((unsigned short*)sg.out)[o] = f2bf(v);
    }
}

// ---------------------------------------------------------------------------
// reduce 3 bf16 split-K partials + fused bias + BN3 + ReLU -> d_out[192:384) f32
// ---------------------------------------------------------------------------
__global__ __launch_bounds__(256)
void reduce_up_kernel(const unsigned short* __restrict__ part,
                      const float* __restrict__ c3b,
                      const float* __restrict__ bn3g, const float* __restrict__ bn3b,
                      float* __restrict__ out) {
    int tid = blockIdx.x * 256 + threadIdx.x;   // 221184
    int e = tid * 4;
    int b = e / 442368; int r = e - b * 442368;
    int o = r / 2304;
    ushort4 p0 = *(const ushort4*)(part + e);
    ushort4 p1 = *(const ushort4*)(part + 884736 + e);
    ushort4 p2 = *(const ushort4*)(part + 1769472 + e);
    float g = bn3g[o], bb = bn3b[o], cb = c3b[o];
    float4 res;
    float* rp = (float*)&res;
    unsigned short* q0 = (unsigned short*)&p0;
    unsigned short* q1 = (unsigned short*)&p1;
    unsigned short* q2 = (unsigned short*)&p2;
    #pragma unroll
    for (int j = 0; j < 4; ++j) {
        float v = bf2f(q0[j]) + bf2f(q1[j]) + bf2f(q2[j]) + cb;
        rp[j] = fmaxf(fmaf(v, g, bb), 0.f);
    }
    *(float4*)(out + (long)b * 884736 + 442368 + r) = res;
}

// ---------------------------------------------------------------------------
// Fused MFMA flash attention, v3: coalesced LDS staging (K,V), 4 waves each
// owning 32 queries (2 q-frags) x 64 keys (hf half of KVBLK=128) -> K/V
// fragment reads amortized over 2x MFMAs vs r7. P via packed-uint2 LDS
// round-trip (wave-private). K pad cols 48..63 zeroed once. Register prefetch
// of next tile before compute. Grid 576 = 36 qblocks(64q) x 16 bh, 256 thr.
// ---------------------------------------------------------------------------
__global__ __launch_bounds__(256)
void attn_kernel(const unsigned short* __restrict__ QK,
                 const unsigned short* __restrict__ Vc,
                 unsigned short* __restrict__ Zt)
{
    int nid = swzb(blockIdx.x, 576);
    int qb = nid % 36;
    int bh = nid / 36;
    int b = bh >> 3, h = bh & 7;
    const unsigned short* Qg = QK + (long)b * NYc * 768 + h * 48;
    const unsigned short* Kg = Qg + 384;
    const unsigned short* Vg = Vc + ((long)b * Dc + h * 24) * NYc;
    unsigned short*       Z  = Zt + (long)b * NYc * Dc + h * 24;

    __shared__ __align__(16) unsigned short Ks[128][72];   // 18.4 KB
    __shared__ __align__(16) unsigned short Vs[24][136];   //  6.5 KB
    __shared__ __align__(16) uint2 Ps[4][2][16][18];       // 18.4 KB (combine alias)

    int t = threadIdx.x, lane = t & 63, w = t >> 6;
    int lr = lane & 15, lg = lane >> 4;
    int tm = w >> 1, hf = w & 1;
    int q0 = qb * 64;

    short8 z8 = {0, 0, 0, 0, 0, 0, 0, 0};
    short8 bq[2][2];
    #pragma unroll
    for (int qf = 0; qf < 2; ++qf) {
        const unsigned short* qrow = Qg + (long)(q0 + tm * 32 + qf * 16 + lr) * 768;
        bq[qf][0] = *(const short8*)(qrow + lg * 8);
        bq[qf][1] = (lg < 2) ? *(const short8*)(qrow + 32 + lg * 8) : z8;
    }

    {   // zero K pad slots 6,7 once (cols 48..63 stay zero all iterations)
        int row = t >> 1, sl = 6 + (t & 1);
        *(uint4*)&Ks[row][sl * 8] = make_uint4(0, 0, 0, 0);
    }

    uint4 kreg[3]; uint4 vreg[2];
    auto ldKV = [&](long k0) {
        #pragma unroll
        for (int i = 0; i < 3; ++i) {          // K: 128 rows x 6 slots (96B data)
            int idx = t + i * 256; int row = idx / 6, sl = idx - row * 6;
            kreg[i] = *(const uint4*)(Kg + (k0 + row) * 768 + sl * 8);
        }
        #pragma unroll
        for (int i = 0; i < 2; ++i) {          // V: 24 rows x 16 slots
            int idx = t + i * 256;
            if (idx < 384) {
                int row = idx >> 4, sl = idx & 15;
                vreg[i] = *(const uint4*)(Vg + (long)row * NYc + k0 + sl * 8);
            }
        }
    };
    auto stKV = [&]() {
        #pragma unroll
        for (int i = 0; i < 3; ++i) {
            int idx = t + i * 256; int row = idx / 6, sl = idx - row * 6;
            *(uint4*)&Ks[row][sl * 8] = kreg[i];
        }
        #pragma unroll
        for (int i = 0; i < 2; ++i) {
            int idx = t + i * 256;
            if (idx < 384) {
                int row = idx >> 4, sl = idx & 15;
                *(uint4*)&Vs[row][sl * 8] = vreg[i];
            }
        }
    };

    float m_run[2] = {-1e30f, -1e30f}, l_run[2] = {0.f, 0.f};
    f32x4 O[2][2];
    #pragma unroll
    for (int qf = 0; qf < 2; ++qf)
        #pragma unroll
        for (int dvf = 0; dvf < 2; ++dvf)
            O[qf][dvf] = (f32x4){0.f, 0.f, 0.f, 0.f};

    ldKV(0); stKV(); __syncthreads();

    for (int kt = 0; kt < 18; ++kt) {
        if (kt < 17) ldKV((long)(kt + 1) * 128);    // prefetch next tile to regs

        // QK^T: lane (lr,lg) gets S[key = ks*16+lg*4+r][q = lr] per q-frag
        f32x4 sS[2][4];
        #pragma unroll
        for (int ks = 0; ks < 4; ++ks) {
            int krow = hf * 64 + ks * 16 + lr;
            short8 ak0 = *(const short8*)&Ks[krow][lg * 8];
            short8 ak1 = *(const short8*)&Ks[krow][32 + lg * 8];
            #pragma unroll
            for (int qf = 0; qf < 2; ++qf) {
                f32x4 c = {0.f, 0.f, 0.f, 0.f};
                c = __builtin_amdgcn_mfma_f32_16x16x32_bf16(ak0, bq[qf][0], c, 0, 0, 0);
                c = __builtin_amdgcn_mfma_f32_16x16x32_bf16(ak1, bq[qf][1], c, 0, 0, 0);
                sS[qf][ks] = c;
            }
        }

        // online softmax per q-frag (q = lr; reduce across lg via xor 16/32)
        #pragma unroll
        for (int qf = 0; qf < 2; ++qf) {
            float tmax = -1e30f;
            #pragma unroll
            for (int ks = 0; ks < 4; ++ks)
                #pragma unroll
                for (int r = 0; r < 4; ++r) tmax = fmaxf(tmax, sS[qf][ks][r]);
            tmax = fmaxf(tmax, __shfl_xor(tmax, 16));
            tmax = fmaxf(tmax, __shfl_xor(tmax, 32));

            if (__any(tmax > m_run[qf] + 10.f)) {   // deferred rescale (rare)
                float mn = fmaxf(m_run[qf], tmax);
                float al = fexp2(m_run[qf] - mn);
                m_run[qf] = mn;
                l_run[qf] *= al;
                #pragma unroll
                for (int rr = 0; rr < 4; ++rr) {
                    float arr = __shfl(al, (lane & 48) | (lg * 4 + rr));
                    O[qf][0][rr] *= arr; O[qf][1][rr] *= arr;
                }
            }

            float psum = 0.f;
            #pragma unroll
            for (int ks = 0; ks < 4; ++ks) {
                float p0 = fexp2(sS[qf][ks][0] - m_run[qf]);
                float p1 = fexp2(sS[qf][ks][1] - m_run[qf]);
                float p2 = fexp2(sS[qf][ks][2] - m_run[qf]);
                float p3 = fexp2(sS[qf][ks][3] - m_run[qf]);
                psum += (p0 + p1) + (p2 + p3);
                uint2 u = { cvtpk(p0, p1), cvtpk(p2, p3) };
                Ps[w][qf][lr][4 * ks + lg] = u;     // b64, wave-private
            }
            psum += __shfl_xor(psum, 16);
            psum += __shfl_xor(psum, 32);
            l_run[qf] += psum;
        }

        // O += P V  (A = P rows q, B = V rows dv; both k-contig over 32 keys)
        #pragma unroll
        for (int ksl = 0; ksl < 2; ++ksl) {
            int vcol = hf * 64 + ksl * 32 + lg * 8;
            short8 bv0 = *(const short8*)&Vs[lr][vcol];
            short8 bv1 = z8;
            if (lr < 8) bv1 = *(const short8*)&Vs[16 + lr][vcol];
            #pragma unroll
            for (int qf = 0; qf < 2; ++qf) {
                short8 ap = *(const short8*)&Ps[w][qf][lr][ksl * 8];
                O[qf][0] = __builtin_amdgcn_mfma_f32_16x16x32_bf16(ap, bv0, O[qf][0], 0, 0, 0);
                O[qf][1] = __builtin_amdgcn_mfma_f32_16x16x32_bf16(ap, bv1, O[qf][1], 0, 0, 0);
            }
        }

        __syncthreads();                            // all reads of tile done
        if (kt < 17) { stKV(); __syncthreads(); }   // write next tile
    }

    // combine the two hf waves of each tm (scratch aliases Ps; barrier above drained)
    float* Cf = (float*)&Ps[0][0][0][0];
    float* T = Cf + tm * 1792;
    if (hf == 1) {
        #pragma unroll
        for (int qf = 0; qf < 2; ++qf)
            #pragma unroll
            for (int dvf = 0; dvf < 2; ++dvf)
                #pragma unroll
                for (int j = 0; j < 4; ++j)
                    T[lane * 16 + qf * 8 + dvf * 4 + j] = O[qf][dvf][j];
        if (lane < 16) {
            T[1024 + lane] = m_run[0]; T[1040 + lane] = l_run[0];
            T[1056 + lane] = m_run[1]; T[1072 + lane] = l_run[1];
        }
    }
    __syncthreads();
    if (hf == 0) {
        #pragma unroll
        for (int qf = 0; qf < 2; ++qf) {
            float mB = T[1024 + qf * 32 + lr], lB = T[1040 + qf * 32 + lr];
            float mS = fmaxf(m_run[qf], mB);
            float aA = fexp2(m_run[qf] - mS), aB = fexp2(mB - mS);
            float invl = 1.f / (l_run[qf] * aA + lB * aB);
            float fA = aA * invl, fB = aB * invl;
            #pragma unroll
            for (int rr = 0; rr < 4; ++rr) {
                int src = (lane & 48) | (lg * 4 + rr);
                float gA = __shfl(fA, src), gB = __shfl(fB, src);
                int n = q0 + tm * 32 + qf * 16 + lg * 4 + rr;
                unsigned short* zr = Z + (long)n * Dc;
                float z0 = O[qf][0][rr] * gA + T[lane * 16 + qf * 8 + rr] * gB;
                zr[lr] = f2bf(z0);
                if (lr < 8) {
                    float z1 = O[qf][1][rr] * gA + T[lane * 16 + qf * 8 + 4 + rr] * gB;
                    zr[16 + lr] = f2bf(z1);
                }
            }
        }
    }
}

// ---------------------------------------------------------------------------
extern "C" void kernel_launch(void* const* d_in, const int* in_sizes, int n_in,
                              void* d_out, int out_size, void* d_ws, size_t ws_size,
                              hipStream_t stream) {
    const float* y       = (const float*)d_in[0];
    const float* s       = (const float*)d_in[1];
    const float* wq_w    = (const float*)d_in[2];
    const float* wq_b    = (const float*)d_in[3];
    const float* wk_w    = (const float*)d_in[4];
    const float* wk_b    = (const float*)d_in[5];
    const float* wv_w    = (const float*)d_in[6];
    const float* wv_b    = (const float*)d_in[7];
    const float* conv1_w = (const float*)d_in[8];
    const float* conv1_b = (const float*)d_in[9];
    const float* bn1_g   = (const float*)d_in[10];
    const float* bn1_b   = (const float*)d_in[11];
    const float* conv2_w = (const float*)d_in[12];
    const float* conv2_b = (const float*)d_in[13];
    const float* bn2_g   = (const float*)d_in[14];
    const float* bn2_b   = (const float*)d_in[15];
    const float* up_w    = (const float*)d_in[16];
    const float* up_b    = (const float*)d_in[17];
    const float* conv3_w = (const float*)d_in[18];
    const float* conv3_b = (const float*)d_in[19];
    const float* bn3_g   = (const float*)d_in[20];
    const float* bn3_b   = (const float*)d_in[21];
    const float* sig_w   = (const float*)d_in[22];
    const float* sig_b   = (const float*)d_in[23];
    const float* bnsig_g = (const float*)d_in[24];
    const float* bnsig_b = (const float*)d_in[25];

    unsigned short* wsp   = (unsigned short*)d_ws;
    unsigned short* wcvt  = wsp;                     // 626688
    unsigned short* upT   = wcvt + 626688;           // 1327104 [3456][384]
    unsigned short* Wc    = upT + 1327104;           //  663552 [192][3456]
    unsigned short* y_pe  = Wc + 663552;             // 1769472 [4608][384]
    unsigned short* s_pe  = y_pe + 1769472;          //  884736 [4608][192]
    unsigned short* y_c1  = s_pe + 884736;           // 1769472
    unsigned short* s_c2  = y_c1 + 1769472;          //  884736
    unsigned short* QKtok = s_c2 + 884736;           // 3538944 [4608][768]
    unsigned short* Vch   = QKtok + 3538944;         //  884736 [b][192][2304]
    unsigned short* partZ = Vch + 884736;            // 2654208 (partials; Ztok aliases)
    unsigned short* Ztok  = partZ;                   //  884736 (lifetime disjoint)
    float*          s_ch  = (float*)(partZ + 2654208); // 884736 fp32
    float*          qkb   = s_ch + 884736;           //  768 fp32
    float*          c3b   = qkb + 768;               //  192 fp32
    float*          peY   = c3b + 192;               //  18432 fp32
    float*          peS   = peY + 18432;             //  9216 fp32

    const unsigned short* conv1wb = wcvt;
    const unsigned short* wqkb    = wcvt + 147456;   // wq||wk, 768 x 384
    const unsigned short* conv2wb = wcvt + 442368;
    const unsigned short* wvb     = wcvt + 479232;
    const unsigned short* sigwb   = wcvt + 516096;
    const unsigned short* conv3wb = wcvt + 552960;

    build_pe_kernel<<<108, 256, 0, stream>>>(peY, peS);
    prep_w_kernel<<<7633, 256, 0, stream>>>(conv1_w, wq_w, wk_w, conv2_w,
                                            wv_w, sig_w, conv3_w, wcvt,
                                            wq_b, wk_b, qkb, up_w, upT,
                                            up_b, conv3_b, c3b);
    prep_pe_kernel<<<648, 256, 0, stream>>>(y, s, peY, peS, y_pe, s_pe, s_ch);

    Seg sz = {};

    // W' = conv3_w @ up_w : A=conv3wb [192][384], B=upT [3456][384] -> Wc [192][3456]
    {
        Seg a = { conv3wb, upT, 384, 384, 384, 54, 0, 162, 32, 1, 0,
                  nullptr, nullptr, nullptr, (char*)Wc, 3456, 0 };
        fused_gemm<1><<<162, 256, 0, stream>>>(a, sz, sz, nullptr);
    }
    // G1: combined up*conv3 split-K=3 (648) + conv1 (432) + conv2 (216) -> 1296
    {
        Seg a = { Wc, y_pe, 3456, 384, 1152, 72, 0, 648, 1 | 8 | 32, 3,
                  (long)884736 * 2,
                  nullptr, nullptr, nullptr, (char*)partZ, NYc, 442368 };
        Seg b = { y_pe, conv1wb, 384, 384, 384, 6, 648, 432, 2, 1, 0,
                  conv1_b, bn1_g, bn1_b, (char*)y_c1, 384, 0 };
        Seg c = { s_pe, conv2wb, 192, 192, 192, 3, 1080, 216, 2, 1, 0,
                  conv2_b, bn2_g, bn2_b, (char*)s_c2, 192, 0 };
        fused_gemm<3><<<1296, 256, 0, stream>>>(a, b, c, nullptr);
    }
    // G2: QK (864) + V (216) -> 1080
    {
        Seg a = { y_c1, wqkb, 384, 384, 384, 12, 0, 864, 0, 1, 0,
                  qkb, nullptr, nullptr, (char*)QKtok, 768, 0 };
        Seg b = { wvb, s_c2, 192, 192, 192, 72, 864, 216, 8, 1, 0,
                  wv_b, nullptr, nullptr, (char*)Vch, NYc, 442368 };
        fused_gemm<2><<<1080, 256, 0, stream>>>(a, b, sz, nullptr);
    }
    // reduce split-K partials -> d_out[192:384) fp32 (with bn3+relu)
    reduce_up_kernel<<<864, 256, 0, stream>>>(partZ, c3b, bn3_g, bn3_b,
                                              (float*)d_out);
    // attention (LDS-staged, 2 q-frags/wave)
    attn_kernel<<<576, 256, 0, stream>>>(QKtok, Vch, Ztok);
    // G4: sigmoid gate (216)
    {
        Seg a = { sigwb, Ztok, 192, 192, 192, 72, 0, 216, 4 | 8 | 16, 1, 0,
                  sig_b, bnsig_g, bnsig_b, (char*)d_out, NYc, 884736 };
        fused_gemm<1><<<216, 256, 0, stream>>>(a, sz, sz, s_ch);
    }
}

// Round 10
// 198.426 us; speedup vs baseline: 1.2051x; 1.1308x over previous
//
#include <hip/hip_runtime.h>
#include <hip/hip_bf16.h>

#define Dc   192
#define D2c  384
#define NYc  2304   // 48*48

// 1/sqrt(192) * log2(e): folded into wq weights+bias so QK^T scores are in
// log2 domain and softmax uses raw v_exp_f32 (= 2^x).
#define QSCALE 0.1041175462f

typedef __attribute__((ext_vector_type(8))) short short8;
typedef __attribute__((ext_vector_type(4))) float f32x4;

__device__ __forceinline__ unsigned short f2bf(float f) {
    unsigned int u = __float_as_uint(f);
    u += 0x7FFFu + ((u >> 16) & 1u);   // RNE
    return (unsigned short)(u >> 16);
}
__device__ __forceinline__ float bf2f(unsigned short u) {
    return __uint_as_float((unsigned)u << 16);
}
__device__ __forceinline__ float fexp2(float x) {
    float r; asm("v_exp_f32 %0, %1" : "=v"(r) : "v"(x)); return r;
}
__device__ __forceinline__ unsigned cvtpk(float lo, float hi) {
    unsigned r; asm("v_cvt_pk_bf16_f32 %0, %1, %2" : "=v"(r) : "v"(lo), "v"(hi));
    return r;
}
// bijective XCD-chunk swizzle (any nwg)
__device__ __forceinline__ int swzb(int orig, int nwg) {
    int q = nwg >> 3, r = nwg & 7, x = orig & 7;
    int base = (x < r) ? x * (q + 1) : r * (q + 1) + (x - r) * q;
    return base + (orig >> 3);
}

// ---------------------------------------------------------------------------
// pe2d tables: peY[c][p] (384x48), peS[c][p] (192x48)
// ---------------------------------------------------------------------------
__global__ __launch_bounds__(256)
void build_pe_kernel(float* __restrict__ peY, float* __restrict__ peS) {
    int idx = blockIdx.x * 256 + threadIdx.x;    // 27648 total
    int c, p, C; float* dst; int off;
    if (idx < 18432) { c = idx / 48; p = idx % 48; C = 384; dst = peY; off = idx; }
    else { int k = idx - 18432; c = k / 48; p = k % 48; C = 192; dst = peS; off = k; }
    int dh = C >> 1;
    int i = ((c < dh) ? c : c - dh) >> 1;
    float divv = expf((float)(2 * i) * (-9.210340371976184f / (float)dh));
    float ang = (float)p * divv;
    dst[off] = (c & 1) ? cosf(ang) : sinf(ang);
}

// PE add + LDS-tiled transpose to token-major bf16 (y and s; s keeps fp32 ch-major)
__global__ __launch_bounds__(256)
void prep_pe_kernel(const float* __restrict__ y, const float* __restrict__ s,
                    const float* __restrict__ peY, const float* __restrict__ peS,
                    unsigned short* __restrict__ ytok, unsigned short* __restrict__ stok,
                    float* __restrict__ sch) {
    __shared__ unsigned short T[64][66];
    int bid = blockIdx.x;
    int b, ct, nt, C; const float* in; const float* pe; unsigned short* outp; bool isS;
    if (bid < 432) { isS = false; b = bid / 216; int r = bid % 216; ct = r / 36; nt = r % 36;
                     in = y; pe = peY; outp = ytok; C = 384; }
    else { int l = bid - 432; isS = true; b = l / 108; int r = l % 108; ct = r / 36; nt = r % 36;
           in = s; pe = peS; outp = stok; C = 192; }
    int t = threadIdx.x;
    int nl = t & 63;
    int n = nt * 64 + nl;
    int pos_x = n % 48, pos_y = n / 48;
    #pragma unroll
    for (int i = 0; i < 16; ++i) {
        int cl = (t >> 6) + 4 * i;
        int c = ct * 64 + cl;
        int pos = (c < (C >> 1)) ? pos_x : pos_y;
        long gi = (long)b * C * NYc + (long)c * NYc + n;
        float v = in[gi] + pe[c * 48 + pos];
        if (isS) sch[gi] = v;
        T[nl][cl] = f2bf(v);
    }
    __syncthreads();
    #pragma unroll
    for (int i = 0; i < 8; ++i) {
        int nl2 = (t >> 5) + 8 * i;
        int cp  = t & 31;
        unsigned u = (unsigned)T[nl2][2 * cp] | ((unsigned)T[nl2][2 * cp + 1] << 16);
        long row = (long)b * NYc + nt * 64 + nl2;
        *(unsigned*)(outp + row * C + ct * 64 + 2 * cp) = u;
    }
}

// weights: seven 1x1 mats bf16 (wq pre-scaled) + qk bias + up_w transpose to
// upT [j=tap*384+c][m] + c3b[o] = conv3_w[o,:]@up_b + conv3_b[o]
__global__ __launch_bounds__(256)
void prep_w_kernel(const float* __restrict__ w0, const float* __restrict__ w1,
                   const float* __restrict__ w2, const float* __restrict__ w3,
                   const float* __restrict__ w4, const float* __restrict__ w5,
                   const float* __restrict__ w6, unsigned short* __restrict__ dst,
                   const float* __restrict__ wq_b, const float* __restrict__ wk_b,
                   float* __restrict__ qkb,
                   const float* __restrict__ upw, unsigned short* __restrict__ upT,
                   const float* __restrict__ up_b, const float* __restrict__ conv3_b,
                   float* __restrict__ c3b) {
    int idx = blockIdx.x * 256 + threadIdx.x;    // 1953792 + 192
    if (idx < 626688) {
        if (idx < 768)
            qkb[idx] = (idx < 384) ? wq_b[idx] * QSCALE : wk_b[idx - 384];
        const float* src; int off; float scl = 1.0f;
        if      (idx < 147456) { src = w0; off = idx; }
        else if (idx < 294912) { src = w1; off = idx - 147456; scl = QSCALE; }
        else if (idx < 442368) { src = w2; off = idx - 294912; }
        else if (idx < 479232) { src = w3; off = idx - 442368; }
        else if (idx < 516096) { src = w4; off = idx - 479232; }
        else if (idx < 552960) { src = w5; off = idx - 516096; }
        else                   { src = w6; off = idx - 552960; }
        dst[idx] = f2bf(src[off] * scl);
    } else if (idx < 1953792) {
        int k = idx - 626688;                    // upT[j][m] = up_w[m][c][tap]
        int j = k / 384, m = k % 384;
        int tap = j / 384, c = j % 384;
        upT[k] = f2bf(upw[((long)m * 384 + c) * 9 + tap]);
    } else if (idx < 1953984) {
        int o = idx - 1953792;                   // c3b fold (w6 = conv3_w)
        float acc = 0.f;
        for (int m = 0; m < 384; ++m) acc += w6[o * 384 + m] * up_b[m];
        c3b[o] = acc + conv3_b[o];
    }
}

// ---------------------------------------------------------------------------
// Fused multi-segment bf16 MFMA GEMM. 64x64 tile, 4 waves (32x32), BK=64,
// double-buffered LDS (one barrier per K-step).
// flags: 1=B-side im2col, 2=BN+ReLU, 4=f32 out, 8=ch-major out, 16=sig-gate,
//        32=no bias.
// ---------------------------------------------------------------------------
struct Seg {
    const unsigned short* A; const unsigned short* B;
    int aP, bP, K, nT, blkOff, nBlk, flags, nSplit;
    long oSplitBytes;
    const float *bias, *bng, *bnb;
    char* out; int oPitch; long oBatch;
};

template<int NSEG>
__global__ __launch_bounds__(256)
void fused_gemm(Seg s0, Seg s1, Seg s2, const float* __restrict__ smul)
{
    int raw = blockIdx.x;
    Seg sg = s0;
    if (NSEG > 1 && raw >= s1.blkOff) sg = s1;
    if (NSEG > 2 && raw >= s2.blkOff) sg = s2;
    int local = swzb(raw - sg.blkOff, sg.nBlk);
    int kBase = 0;
    if (sg.nSplit > 1) {
        int pc = sg.nBlk / sg.nSplit;
        int g = local / pc; local -= g * pc;
        sg.A += (long)g * sg.K;
        sg.out += (long)g * sg.oSplitBytes;
        kBase = g * sg.K;
    }
    int mt = local / sg.nT, nt = local - mt * sg.nT;
    int m0 = mt * 64, n0 = nt * 64;

    __shared__ __align__(16) unsigned short As[2][64][72];
    __shared__ __align__(16) unsigned short Bs[2][64][72];

    int t = threadIdx.x, lane = t & 63, w = t >> 6;
    int lr = lane & 15, lg = lane >> 4;
    int wm = (w >> 1) * 32, wn = (w & 1) * 32;

    f32x4 acc[2][2];
    #pragma unroll
    for (int i = 0; i < 2; ++i)
        #pragma unroll
        for (int j = 0; j < 2; ++j)
            acc[i][j] = (f32x4){0.f, 0.f, 0.f, 0.f};

    uint4 ra[2], rb[2];
    bool im2colB = (sg.flags & 1) != 0;

    auto load = [&](int k0) {
        #pragma unroll
        for (int i = 0; i < 2; ++i) {
            int idx = t + i * 256, row = idx >> 3, sl = idx & 7;
            ra[i] = *(const uint4*)(sg.A + (long)(m0 + row) * sg.aP + k0 + sl * 8);
            if (im2colB) {
                int tok = n0 + row;
                int bb = tok >= NYc;
                int n = tok - bb * NYc;
                int kk = kBase + k0;
                int tap = kk / 384;
                int rem = kk - tap * 384 + sl * 8;
                int py = n / 48 + tap / 3 - 1;
                int px = n % 48 + tap % 3 - 1;
                rb[i] = (py >= 0 && py < 48 && px >= 0 && px < 48)
                    ? *(const uint4*)(sg.B + ((long)bb * NYc + py * 48 + px) * sg.bP + rem)
                    : make_uint4(0, 0, 0, 0);
            } else {
                rb[i] = *(const uint4*)(sg.B + (long)(n0 + row) * sg.bP + k0 + sl * 8);
            }
        }
    };
    auto store = [&](int buf) {
        #pragma unroll
        for (int i = 0; i < 2; ++i) {
            int idx = t + i * 256;
            *(uint4*)&As[buf][idx >> 3][(idx & 7) * 8] = ra[i];
            *(uint4*)&Bs[buf][idx >> 3][(idx & 7) * 8] = rb[i];
        }
    };

    load(0); store(0); __syncthreads();
    int NT = sg.K >> 6;
    int cur = 0;
    for (int tt = 0; tt < NT; ++tt) {
        bool more = (tt + 1 < NT);
        if (more) load((tt + 1) << 6);           // issue-early prefetch
        #pragma unroll
        for (int kk = 0; kk < 2; ++kk) {
            short8 a0 = *(const short8*)&As[cur][wm + lr][kk * 32 + lg * 8];
            short8 a1 = *(const short8*)&As[cur][wm + 16 + lr][kk * 32 + lg * 8];
            short8 b0 = *(const short8*)&Bs[cur][wn + lr][kk * 32 + lg * 8];
            short8 b1 = *(const short8*)&Bs[cur][wn + 16 + lr][kk * 32 + lg * 8];
            acc[0][0] = __builtin_amdgcn_mfma_f32_16x16x32_bf16(a0, b0, acc[0][0], 0, 0, 0);
            acc[0][1] = __builtin_amdgcn_mfma_f32_16x16x32_bf16(a0, b1, acc[0][1], 0, 0, 0);
            acc[1][0] = __builtin_amdgcn_mfma_f32_16x16x32_bf16(a1, b0, acc[1][0], 0, 0, 0);
            acc[1][1] = __builtin_amdgcn_mfma_f32_16x16x32_bf16(a1, b1, acc[1][1], 0, 0, 0);
        }
        if (more) store(cur ^ 1);                // other buffer: no pre-barrier
        __syncthreads();
        cur ^= 1;
    }

    #pragma unroll
    for (int i = 0; i < 2; ++i)
    #pragma unroll
    for (int j = 0; j < 2; ++j)
    #pragma unroll
    for (int r = 0; r < 4; ++r) {
        int gm = m0 + wm + i * 16 + lg * 4 + r;
        int gn = n0 + wn + j * 16 + lr;
        int ch = (sg.flags & 8) ? gm : gn;
        float v = acc[i][j][r];
        if (!(sg.flags & 32)) v += sg.bias[ch];
        if (sg.flags & 2)
            v = fmaxf(fmaf(v, sg.bng[ch], sg.bnb[ch]), 0.f);
        long o; int b = 0, tok = gn;
        if (sg.flags & 8) {
            b = gn >= NYc; tok = gn - b * NYc;
            o = (long)b * sg.oBatch + (long)gm * sg.oPitch + tok;
        } else {
            o = (long)gm * sg.oPitch + gn;
        }
        if (sg.flags & 16) {
            v = fmaf(v, sg.bng[ch], sg.bnb[ch]);
            v = 1.f / (1.f + __expf(-v));
            v *= smul[(long)b * 442368 + (long)gm * NYc + tok];
        }
        if (sg.flags & 4) ((float*)sg.out)[o] = v;
        else              ((unsigned short*)sg.out)[o] = f2bf(v);
    }
}

// ---------------------------------------------------------------------------
// reduce 3 bf16 split-K partials + fused bias + BN3 + ReLU -> d_out[192:384) f32
// ---------------------------------------------------------------------------
__global__ __launch_bounds__(256)
void reduce_up_kernel(const unsigned short* __restrict__ part,
                      const float* __restrict__ c3b,
                      const float* __restrict__ bn3g, const float* __restrict__ bn3b,
                      float* __restrict__ out) {
    int tid = blockIdx.x * 256 + threadIdx.x;   // 221184
    int e = tid * 4;
    int b = e / 442368; int r = e - b * 442368;
    int o = r / 2304;
    ushort4 p0 = *(const ushort4*)(part + e);
    ushort4 p1 = *(const ushort4*)(part + 884736 + e);
    ushort4 p2 = *(const ushort4*)(part + 1769472 + e);
    float g = bn3g[o], bb = bn3b[o], cb = c3b[o];
    float4 res;
    float* rp = (float*)&res;
    unsigned short* q0 = (unsigned short*)&p0;
    unsigned short* q1 = (unsigned short*)&p1;
    unsigned short* q2 = (unsigned short*)&p2;
    #pragma unroll
    for (int j = 0; j < 4; ++j) {
        float v = bf2f(q0[j]) + bf2f(q1[j]) + bf2f(q2[j]) + cb;
        rp[j] = fmaxf(fmaf(v, g, bb), 0.f);
    }
    *(float4*)(out + (long)b * 884736 + 442368 + r) = res;
}

// ---------------------------------------------------------------------------
// Fused MFMA flash attention, round-7 structure + KV-split=2 (flash-decoding).
// Grid 1152 = 36 qb x 16 bh x 2 sp; 512 thr = 8 waves = 4 q-teams x 2 hf key
// halves. Each block: 1152 keys (9 tiles of 128). Writes UNNORMALIZED partial
// O (fp32) + per-q (m,l) to workspace; attn_combine merges the 2 splits.
// K staged 6 slots/row (pad cols 48..63 zeroed once); register prefetch.
// ---------------------------------------------------------------------------
__global__ __launch_bounds__(512)
void attn_kernel(const unsigned short* __restrict__ QK,
                 const unsigned short* __restrict__ Vc,
                 float* __restrict__ Opart, float* __restrict__ mlpart)
{
    int nid = swzb(blockIdx.x, 1152);
    int qb = nid % 36;
    int bh = (nid / 36) & 15;
    int sp = nid / 576;
    int b = bh >> 3, h = bh & 7;
    const unsigned short* Qg = QK + (long)b * NYc * 768 + h * 48;
    const unsigned short* Kg = Qg + 384;
    const unsigned short* Vg = Vc + ((long)b * Dc + h * 24) * NYc;

    __shared__ __align__(16) unsigned short Ks[128][72];   // 18.4 KB
    __shared__ __align__(16) unsigned short Vs[24][136];   //  6.5 KB
    __shared__ __align__(16) uint2 Ps[8][16][18];          // 18.4 KB (combine alias)

    int t = threadIdx.x, lane = t & 63, w = t >> 6;
    int lr = lane & 15, lg = lane >> 4;
    int tm = w >> 1, hf = w & 1;
    int q0 = qb * 64;
    long kbase = (long)sp * 1152;

    short8 z8 = {0, 0, 0, 0, 0, 0, 0, 0};
    const unsigned short* qrow = Qg + (long)(q0 + tm * 16 + lr) * 768;
    short8 bq0 = *(const short8*)(qrow + lg * 8);
    short8 bq1 = (lg < 2) ? *(const short8*)(qrow + 32 + lg * 8) : z8;

    if (t < 256) {   // zero K pad slots 6,7 once (cols 48..63 stay zero)
        int row = t >> 1, sl = 6 + (t & 1);
        *(uint4*)&Ks[row][sl * 8] = make_uint4(0, 0, 0, 0);
    }

    uint4 kreg[2]; uint4 vreg;
    auto ldKV = [&](long k0) {
        #pragma unroll
        for (int i = 0; i < 2; ++i) {          // K: 128 rows x 6 slots (96B data)
            int idx = t + i * 512;
            if (idx < 768) {
                int row = idx / 6, sl = idx - row * 6;
                kreg[i] = *(const uint4*)(Kg + (k0 + row) * 768 + sl * 8);
            }
        }
        if (t < 384) {                         // V: 24 rows x 16 slots
            int row = t >> 4, sl = t & 15;
            vreg = *(const uint4*)(Vg + (long)row * NYc + k0 + sl * 8);
        }
    };
    auto stKV = [&]() {
        #pragma unroll
        for (int i = 0; i < 2; ++i) {
            int idx = t + i * 512;
            if (idx < 768) {
                int row = idx / 6, sl = idx - row * 6;
                *(uint4*)&Ks[row][sl * 8] = kreg[i];
            }
        }
        if (t < 384) {
            int row = t >> 4, sl = t & 15;
            *(uint4*)&Vs[row][sl * 8] = vreg;
        }
    };

    float m_run = -1e30f, l_run = 0.f;
    f32x4 O0 = {0.f, 0.f, 0.f, 0.f}, O1 = {0.f, 0.f, 0.f, 0.f};

    ldKV(kbase); stKV(); __syncthreads();

    for (int kt = 0; kt < 9; ++kt) {
        if (kt < 8) ldKV(kbase + (long)(kt + 1) * 128);   // prefetch to regs

        // S^T = K Q^T : lane holds S[k = ks*16+lg*4+r][q = lr]
        f32x4 sS[4];
        #pragma unroll
        for (int ks = 0; ks < 4; ++ks) {
            int krow = hf * 64 + ks * 16 + lr;
            short8 ak0 = *(const short8*)&Ks[krow][lg * 8];
            short8 ak1 = *(const short8*)&Ks[krow][32 + lg * 8];
            f32x4 c = {0.f, 0.f, 0.f, 0.f};
            c = __builtin_amdgcn_mfma_f32_16x16x32_bf16(ak0, bq0, c, 0, 0, 0);
            c = __builtin_amdgcn_mfma_f32_16x16x32_bf16(ak1, bq1, c, 0, 0, 0);
            sS[ks] = c;
        }

        float tmax = -1e30f;
        #pragma unroll
        for (int ks = 0; ks < 4; ++ks)
            #pragma unroll
            for (int r = 0; r < 4; ++r) tmax = fmaxf(tmax, sS[ks][r]);
        tmax = fmaxf(tmax, __shfl_xor(tmax, 16));
        tmax = fmaxf(tmax, __shfl_xor(tmax, 32));

        if (__any(tmax > m_run + 10.f)) {       // deferred rescale (rare)
            float mn = fmaxf(m_run, tmax);
            float al = fexp2(m_run - mn);
            m_run = mn;
            l_run *= al;
            #pragma unroll
            for (int rr = 0; rr < 4; ++rr) {
                float arr = __shfl(al, (lane & 48) | (lg * 4 + rr));
                O0[rr] *= arr; O1[rr] *= arr;
            }
        }

        float psum = 0.f;
        #pragma unroll
        for (int ks = 0; ks < 4; ++ks) {
            float p0 = fexp2(sS[ks][0] - m_run);
            float p1 = fexp2(sS[ks][1] - m_run);
            float p2 = fexp2(sS[ks][2] - m_run);
            float p3 = fexp2(sS[ks][3] - m_run);
            psum += (p0 + p1) + (p2 + p3);
            uint2 u = { cvtpk(p0, p1), cvtpk(p2, p3) };
            Ps[w][lr][4 * ks + lg] = u;         // b64, wave-private
        }
        psum += __shfl_xor(psum, 16);
        psum += __shfl_xor(psum, 32);
        l_run += psum;

        // O += P V
        short8 ap0 = *(const short8*)&Ps[w][lr][2 * lg];
        short8 ap1 = *(const short8*)&Ps[w][lr][8 + 2 * lg];
        int vcol0 = hf * 64 + lg * 8;
        short8 bv00 = *(const short8*)&Vs[lr][vcol0];
        short8 bv01 = *(const short8*)&Vs[lr][vcol0 + 32];
        short8 bv10 = z8, bv11 = z8;
        if (lr < 8) {
            bv10 = *(const short8*)&Vs[16 + lr][vcol0];
            bv11 = *(const short8*)&Vs[16 + lr][vcol0 + 32];
        }
        O0 = __builtin_amdgcn_mfma_f32_16x16x32_bf16(ap0, bv00, O0, 0, 0, 0);
        O0 = __builtin_amdgcn_mfma_f32_16x16x32_bf16(ap1, bv01, O0, 0, 0, 0);
        O1 = __builtin_amdgcn_mfma_f32_16x16x32_bf16(ap0, bv10, O1, 0, 0, 0);
        O1 = __builtin_amdgcn_mfma_f32_16x16x32_bf16(ap1, bv11, O1, 0, 0, 0);

        __syncthreads();                         // all reads of tile done
        if (kt < 8) { stKV(); __syncthreads(); } // write next tile
    }

    // merge the two hf waves of each team; write unnormalized partial + (m,l)
    float* Cf = (float*)&Ps[0][0][0];
    float* T = Cf + tm * 576;
    if (hf == 1) {
        #pragma unroll
        for (int j = 0; j < 4; ++j) {
            T[lane * 8 + j]     = O0[j];
            T[lane * 8 + 4 + j] = O1[j];
        }
        if (lane < 16) { T[512 + lane] = m_run; T[528 + lane] = l_run; }
    }
    __syncthreads();
    if (hf == 0) {
        float mB = T[512 + lr], lB = T[528 + lr];
        float mS = fmaxf(m_run, mB);
        float aA = fexp2(m_run - mS), aB = fexp2(mB - mS);
        float lC = l_run * aA + lB * aB;
        #pragma unroll
        for (int rr = 0; rr < 4; ++rr) {
            int src = (lane & 48) | (lg * 4 + rr);
            float gA = __shfl(aA, src), gB = __shfl(aB, src);
            int n = q0 + tm * 16 + lg * 4 + rr;
            float* od = Opart + ((long)(sp * 16 + bh) * NYc + n) * 24;
            od[lr] = O0[rr] * gA + T[lane * 8 + rr] * gB;
            if (lr < 8)
                od[16 + lr] = O1[rr] * gA + T[lane * 8 + 4 + rr] * gB;
        }
        if (lg == 0) {
            int n = q0 + tm * 16 + lr;
            float* md = mlpart + ((long)(sp * 16 + bh) * NYc + n) * 2;
            md[0] = mS; md[1] = lC;
        }
    }
}

// ---------------------------------------------------------------------------
// merge the 2 KV-split partials -> Ztok bf16 [b][n][192]
// ---------------------------------------------------------------------------
__global__ __launch_bounds__(256)
void attn_combine_kernel(const float* __restrict__ Opart,
                         const float* __restrict__ mlpart,
                         unsigned short* __restrict__ Zt) {
    int idx = blockIdx.x * 256 + threadIdx.x;   // 884736 = 16*2304*24
    int dv = idx % 24;
    int n  = (idx / 24) % NYc;
    int bh = idx / (24 * NYc);
    int b = bh >> 3, h = bh & 7;
    const float* ml0 = mlpart + ((long)bh * NYc + n) * 2;
    const float* ml1 = mlpart + ((long)(16 + bh) * NYc + n) * 2;
    float m0 = ml0[0], l0 = ml0[1], m1 = ml1[0], l1 = ml1[1];
    float mS = fmaxf(m0, m1);
    float w0 = fexp2(m0 - mS), w1 = fexp2(m1 - mS);
    float o0 = Opart[((long)bh * NYc + n) * 24 + dv];
    float o1 = Opart[((long)(16 + bh) * NYc + n) * 24 + dv];
    float z = (o0 * w0 + o1 * w1) / (l0 * w0 + l1 * w1);
    Zt[((long)b * NYc + n) * Dc + h * 24 + dv] = f2bf(z);
}

// ---------------------------------------------------------------------------
extern "C" void kernel_launch(void* const* d_in, const int* in_sizes, int n_in,
                              void* d_out, int out_size, void* d_ws, size_t ws_size,
                              hipStream_t stream) {
    const float* y       = (const float*)d_in[0];
    const float* s       = (const float*)d_in[1];
    const float* wq_w    = (const float*)d_in[2];
    const float* wq_b    = (const float*)d_in[3];
    const float* wk_w    = (const float*)d_in[4];
    const float* wk_b    = (const float*)d_in[5];
    const float* wv_w    = (const float*)d_in[6];
    const float* wv_b    = (const float*)d_in[7];
    const float* conv1_w = (const float*)d_in[8];
    const float* conv1_b = (const float*)d_in[9];
    const float* bn1_g   = (const float*)d_in[10];
    const float* bn1_b   = (const float*)d_in[11];
    const float* conv2_w = (const float*)d_in[12];
    const float* conv2_b = (const float*)d_in[13];
    const float* bn2_g   = (const float*)d_in[14];
    const float* bn2_b   = (const float*)d_in[15];
    const float* up_w    = (const float*)d_in[16];
    const float* up_b    = (const float*)d_in[17];
    const float* conv3_w = (const float*)d_in[18];
    const float* conv3_b = (const float*)d_in[19];
    const float* bn3_g   = (const float*)d_in[20];
    const float* bn3_b   = (const float*)d_in[21];
    const float* sig_w   = (const float*)d_in[22];
    const float* sig_b   = (const float*)d_in[23];
    const float* bnsig_g = (const float*)d_in[24];
    const float* bnsig_b = (const float*)d_in[25];

    unsigned short* wsp   = (unsigned short*)d_ws;
    unsigned short* wcvt  = wsp;                     // 626688
    unsigned short* upT   = wcvt + 626688;           // 1327104 [3456][384]
    unsigned short* Wc    = upT + 1327104;           //  663552 [192][3456]
    unsigned short* y_pe  = Wc + 663552;             // 1769472 [4608][384]
    unsigned short* s_pe  = y_pe + 1769472;          //  884736 [4608][192]
    unsigned short* y_c1  = s_pe + 884736;           // 1769472
    unsigned short* s_c2  = y_c1 + 1769472;          //  884736
    unsigned short* QKtok = s_c2 + 884736;           // 3538944 [4608][768]
    unsigned short* Vch   = QKtok + 3538944;         //  884736 [b][192][2304]
    unsigned short* partZ = Vch + 884736;            // 2654208 (partials; Ztok aliases)
    unsigned short* Ztok  = partZ;                   //  884736 (lifetime disjoint)
    float*          s_ch  = (float*)(partZ + 2654208); // 884736 fp32
    float*          qkb   = s_ch + 884736;           //  768 fp32
    float*          c3b   = qkb + 768;               //  192 fp32
    float*          peY   = c3b + 192;               //  18432 fp32
    float*          peS   = peY + 18432;             //  9216 fp32
    // attn flash-decoding partials alias upT..s_pe (dead after G1):
    float*          Opart  = (float*)upT;            // 1769472 fp32 [2][16][2304][24]
    float*          mlpart = Opart + 1769472;        //  147456 fp32 [2][16][2304][2]

    const unsigned short* conv1wb = wcvt;
    const unsigned short* wqkb    = wcvt + 147456;   // wq||wk, 768 x 384
    const unsigned short* conv2wb = wcvt + 442368;
    const unsigned short* wvb     = wcvt + 479232;
    const unsigned short* sigwb   = wcvt + 516096;
    const unsigned short* conv3wb = wcvt + 552960;

    build_pe_kernel<<<108, 256, 0, stream>>>(peY, peS);
    prep_w_kernel<<<7633, 256, 0, stream>>>(conv1_w, wq_w, wk_w, conv2_w,
                                            wv_w, sig_w, conv3_w, wcvt,
                                            wq_b, wk_b, qkb, up_w, upT,
                                            up_b, conv3_b, c3b);
    prep_pe_kernel<<<648, 256, 0, stream>>>(y, s, peY, peS, y_pe, s_pe, s_ch);

    Seg sz = {};

    // W' = conv3_w @ up_w : A=conv3wb [192][384], B=upT [3456][384] -> Wc [192][3456]
    {
        Seg a = { conv3wb, upT, 384, 384, 384, 54, 0, 162, 32, 1, 0,
                  nullptr, nullptr, nullptr, (char*)Wc, 3456, 0 };
        fused_gemm<1><<<162, 256, 0, stream>>>(a, sz, sz, nullptr);
    }
    // G1: combined up*conv3 split-K=3 (648) + conv1 (432) + conv2 (216) -> 1296
    {
        Seg a = { Wc, y_pe, 3456, 384, 1152, 72, 0, 648, 1 | 8 | 32, 3,
                  (long)884736 * 2,
                  nullptr, nullptr, nullptr, (char*)partZ, NYc, 442368 };
        Seg b = { y_pe, conv1wb, 384, 384, 384, 6, 648, 432, 2, 1, 0,
                  conv1_b, bn1_g, bn1_b, (char*)y_c1, 384, 0 };
        Seg c = { s_pe, conv2wb, 192, 192, 192, 3, 1080, 216, 2, 1, 0,
                  conv2_b, bn2_g, bn2_b, (char*)s_c2, 192, 0 };
        fused_gemm<3><<<1296, 256, 0, stream>>>(a, b, c, nullptr);
    }
    // G2: QK (864) + V (216) -> 1080
    {
        Seg a = { y_c1, wqkb, 384, 384, 384, 12, 0, 864, 0, 1, 0,
                  qkb, nullptr, nullptr, (char*)QKtok, 768, 0 };
        Seg b = { wvb, s_c2, 192, 192, 192, 72, 864, 216, 8, 1, 0,
                  wv_b, nullptr, nullptr, (char*)Vch, NYc, 442368 };
        fused_gemm<2><<<1080, 256, 0, stream>>>(a, b, sz, nullptr);
    }
    // reduce split-K partials -> d_out[192:384) fp32 (with bn3+relu)
    reduce_up_kernel<<<864, 256, 0, stream>>>(partZ, c3b, bn3_g, bn3_b,
                                              (float*)d_out);
    // attention: KV-split=2 flash-decoding partials, then combine
    attn_kernel<<<1152, 512, 0, stream>>>(QKtok, Vch, Opart, mlpart);
    attn_combine_kernel<<<3456, 256, 0, stream>>>(Opart, mlpart, Ztok);
    // G4: sigmoid gate (216)
    {
        Seg a = { sigwb, Ztok, 192, 192, 192, 72, 0, 216, 4 | 8 | 16, 1, 0,
                  sig_b, bnsig_g, bnsig_b, (char*)d_out, NYc, 884736 };
        fused_gemm<1><<<216, 256, 0, stream>>>(a, sz, sz, s_ch);
    }
}